// Round 1
// baseline (450.833 us; speedup 1.0000x reference)
//
#include <hip/hip_runtime.h>

// Haar wavelet transform, 14 levels, rows of 16384 f32, batch 64*64 = 4096 rows.
// Output = cA_1 (8192/row) ++ cA_2 ++ ... ++ cA_14 (1/row) ++ cD_14 (1/row).
// cA = (even - odd)/sqrt2, cD = (even + odd)/sqrt2, recurse on cD.
//
// R3 structure:
//  - Levels 1-4 entirely in registers: each thread owns 16 contiguous inputs
//    (4x float4 nontemporal loads) -> cA1 x8 (2x f32x4 stores), cA2 x4 (f32x4),
//    cA3 x2 (f32x2), cA4 x1, cD4 x1 -> LDS.
//  - Levels 5-7 in LDS with a compact ping-pong layout (bufA 4KB / bufB 2KB):
//    all reads are dense ds_read_b128, all writes dense ds_write_b64 ->
//    ZERO bank conflicts (the old in-place strided scheme was 4..32-way
//    conflicted on every level). 3 barriers total instead of 11.
//  - Levels 8-14 in wave-0 registers via __shfl: no LDS, no barriers.
// LDS = 6 KB -> occupancy stays wave-capped at 8 blocks/CU (32 waves/CU).

typedef float f32x4 __attribute__((ext_vector_type(4)));
typedef float f32x2 __attribute__((ext_vector_type(2)));

constexpr int ROW_LEN = 16384;   // 2^14
constexpr int NROWS   = 64 * 64; // 4096
constexpr int NT      = 256;     // threads per block (one block per row)

__global__ __launch_bounds__(NT) void haar_kernel(const float* __restrict__ in,
                                                  float* __restrict__ out) {
    __shared__ __align__(16) float bufA[1024];  // cD4 (4 KB), later cD6 (1 KB)
    __shared__ __align__(16) float bufB[512];   // cD5 (2 KB)

    const int row = blockIdx.x;
    const int tid = threadIdx.x;
    const float K = 0.70710678118654752440f; // 1/sqrt(2)

    const f32x4* rin4 = (const f32x4*)(in + (size_t)row * ROW_LEN);

    f32x4* o1 = (f32x4*)(out + (size_t)row * 8192);
    f32x4* o2 = (f32x4*)(out + (size_t)NROWS * 8192  + (size_t)row * 4096);
    f32x2* o3 = (f32x2*)(out + (size_t)NROWS * 12288 + (size_t)row * 2048);
    float* o4 =          out + (size_t)NROWS * 14336 + (size_t)row * 1024;

    // ---- Levels 1-4 in registers: 16 contiguous elements per thread per iter.
    #pragma unroll
    for (int it = 0; it < ROW_LEN / (16 * NT); ++it) {   // 4 iterations
        const int tp = it * NT + tid;                     // [0, 1024)
        f32x4 v0 = __builtin_nontemporal_load(rin4 + 4 * tp + 0);
        f32x4 v1 = __builtin_nontemporal_load(rin4 + 4 * tp + 1);
        f32x4 v2 = __builtin_nontemporal_load(rin4 + 4 * tp + 2);
        f32x4 v3 = __builtin_nontemporal_load(rin4 + 4 * tp + 3);

        // level 1
        f32x4 ca1a = { (v0.x - v0.y) * K, (v0.z - v0.w) * K,
                       (v1.x - v1.y) * K, (v1.z - v1.w) * K };
        f32x4 ca1b = { (v2.x - v2.y) * K, (v2.z - v2.w) * K,
                       (v3.x - v3.y) * K, (v3.z - v3.w) * K };
        float d0 = (v0.x + v0.y) * K, d1 = (v0.z + v0.w) * K;
        float d2 = (v1.x + v1.y) * K, d3 = (v1.z + v1.w) * K;
        float d4 = (v2.x + v2.y) * K, d5 = (v2.z + v2.w) * K;
        float d6 = (v3.x + v3.y) * K, d7 = (v3.z + v3.w) * K;

        // level 2
        f32x4 ca2 = { (d0 - d1) * K, (d2 - d3) * K,
                      (d4 - d5) * K, (d6 - d7) * K };
        float e0 = (d0 + d1) * K, e1 = (d2 + d3) * K;
        float e2 = (d4 + d5) * K, e3 = (d6 + d7) * K;

        // level 3
        f32x2 ca3 = { (e0 - e1) * K, (e2 - e3) * K };
        float f0 = (e0 + e1) * K, f1 = (e2 + e3) * K;

        // level 4
        float ca4 = (f0 - f1) * K;
        float cd4 = (f0 + f1) * K;

        __builtin_nontemporal_store(ca1a, o1 + 2 * tp);
        __builtin_nontemporal_store(ca1b, o1 + 2 * tp + 1);
        __builtin_nontemporal_store(ca2,  o2 + tp);
        __builtin_nontemporal_store(ca3,  o3 + tp);
        __builtin_nontemporal_store(ca4,  o4 + tp);
        bufA[tp] = cd4;                 // dense: conflict-free
    }
    __syncthreads();

    // ---- Level 5: 512 outputs; each thread handles 2 via one b128 LDS read.
    {
        f32x4 v = ((const f32x4*)bufA)[tid];            // cD4[4t..4t+3]
        f32x2 ca = { (v.x - v.y) * K, (v.z - v.w) * K };
        f32x2 cd = { (v.x + v.y) * K, (v.z + v.w) * K };
        f32x2* o5 = (f32x2*)(out + (size_t)NROWS * 15360 + (size_t)row * 512);
        o5[tid] = ca;
        ((f32x2*)bufB)[tid] = cd;                        // dense: conflict-free
    }
    __syncthreads();

    // ---- Level 6: 256 outputs.
    if (tid < 128) {
        f32x4 v = ((const f32x4*)bufB)[tid];            // cD5[4t..4t+3]
        f32x2 ca = { (v.x - v.y) * K, (v.z - v.w) * K };
        f32x2 cd = { (v.x + v.y) * K, (v.z + v.w) * K };
        f32x2* o6 = (f32x2*)(out + (size_t)NROWS * 15872 + (size_t)row * 256);
        o6[tid] = ca;
        ((f32x2*)bufA)[tid] = cd;
    }
    __syncthreads();

    // ---- Levels 7-14: wave 0 only; no further barriers needed.
    if (tid < 64) {
        // level 7 (128 outputs): read cD6[4t..4t+3]; cD7 pair stays in regs —
        // lane t's cD7[2t], cD7[2t+1] are exactly what level 8 lane t needs.
        f32x4 v = ((const f32x4*)bufA)[tid];
        f32x2 ca7 = { (v.x - v.y) * K, (v.z - v.w) * K };
        f32x2* o7 = (f32x2*)(out + (size_t)NROWS * 16128 + (size_t)row * 128);
        o7[tid] = ca7;
        float cd7a = (v.x + v.y) * K;
        float cd7b = (v.z + v.w) * K;

        // level 8 (64 outputs), purely in registers
        float* o8 = out + (size_t)NROWS * 16256 + (size_t)row * 64;
        o8[tid] = (cd7a - cd7b) * K;
        float x = (cd7a + cd7b) * K;     // cD8[lane]

        // levels 9-14 via cross-lane shuffle; lanes >= n carry garbage that is
        // never read (next level only sources lanes < 2n).
        size_t chunk = (size_t)NROWS * 16320;
        #pragma unroll
        for (int L = 9; L <= 14; ++L) {
            const int n = ROW_LEN >> L;               // 32,16,8,4,2,1
            float even = __shfl(x, 2 * tid,     64);
            float odd  = __shfl(x, 2 * tid + 1, 64);
            float ca = (even - odd) * K;
            x        = (even + odd) * K;
            if (tid < n) out[chunk + (size_t)row * n + tid] = ca;
            chunk += (size_t)NROWS * n;
        }
        // final approximation chunk: cD_14
        if (tid == 0) out[chunk + row] = x;
    }
}

extern "C" void kernel_launch(void* const* d_in, const int* in_sizes, int n_in,
                              void* d_out, int out_size, void* d_ws, size_t ws_size,
                              hipStream_t stream) {
    const float* x = (const float*)d_in[0];
    float* out = (float*)d_out;
    haar_kernel<<<dim3(NROWS), dim3(NT), 0, stream>>>(x, out);
}

// Round 3
// 430.011 us; speedup vs baseline: 1.0484x; 1.0484x over previous
//
#include <hip/hip_runtime.h>

// Haar wavelet transform, 14 levels, rows of 16384 f32, batch 64*64 = 4096 rows.
// Output = cA_1 (8192/row) ++ cA_2 ++ ... ++ cA_14 (1/row) ++ cD_14 (1/row).
// cA = (even - odd)/sqrt2, cD = (even + odd)/sqrt2, recurse on cD.
//
// R4 = R2's streaming phase + conflict-free tail:
//  - Levels 1-3 in registers exactly as R2 (8 contiguous inputs/thread/iter,
//    plain float4 loads, plain stores — keeps VGPR <= 64 so the block stays
//    wave-capped at 8 blocks/CU = 32 waves/CU for full latency hiding).
//    R3's 16-elem/thread + nontemporal variant regressed ~20% (kernel
//    ~100 -> ~120 us): too many live VGPRs halved occupancy.
//  - Levels 4-6 in LDS, compact ping-pong (bufA 8 KB / bufB 4 KB): every LDS
//    read is f32x4 over a CONTIGUOUS index range (words spread evenly over
//    all 32 banks -> conflict-free), writes are dense f32x2. The old R2 tail
//    was in-place strided: 4..32-way bank conflicts on every level + 11
//    barriers. Now 4 barriers total.
//  - Levels 7-14 in wave-0 registers via __shfl: no LDS, no barriers.
// LDS = 12 KB -> still wave-capped occupancy (160/12 = 13 > 8 blocks/CU).

typedef float f32x4 __attribute__((ext_vector_type(4)));
typedef float f32x2 __attribute__((ext_vector_type(2)));

constexpr int ROW_LEN = 16384;   // 2^14
constexpr int NROWS   = 64 * 64; // 4096
constexpr int NT      = 256;     // threads per block (one block per row)

__global__ __launch_bounds__(NT) void haar_kernel(const float* __restrict__ in,
                                                  float* __restrict__ out) {
    __shared__ __align__(16) float bufA[2048];  // cD3 (8 KB), later cD5 (2 KB)
    __shared__ __align__(16) float bufB[1024];  // cD4 (4 KB), later cD6 (1 KB)

    const int row = blockIdx.x;
    const int tid = threadIdx.x;
    const float K = 0.70710678118654752440f; // 1/sqrt(2)

    const f32x4* rin4 = (const f32x4*)(in + (size_t)row * ROW_LEN);

    f32x4* o1 = (f32x4*)(out + (size_t)row * 8192);
    f32x2* o2 = (f32x2*)(out + (size_t)NROWS * 8192  + (size_t)row * 4096);
    float* o3 =          out + (size_t)NROWS * 12288 + (size_t)row * 2048;

    // ---- Levels 1-3 in registers: 8 contiguous elements per thread per iter.
    #pragma unroll
    for (int it = 0; it < ROW_LEN / (8 * NT); ++it) {   // 8 iterations
        const int tp = it * NT + tid;                    // [0, 2048)
        f32x4 v0 = rin4[2 * tp];
        f32x4 v1 = rin4[2 * tp + 1];

        // level 1
        f32x4 ca1;
        ca1.x = (v0.x - v0.y) * K;
        ca1.y = (v0.z - v0.w) * K;
        ca1.z = (v1.x - v1.y) * K;
        ca1.w = (v1.z - v1.w) * K;
        float d0 = (v0.x + v0.y) * K;
        float d1 = (v0.z + v0.w) * K;
        float d2 = (v1.x + v1.y) * K;
        float d3 = (v1.z + v1.w) * K;

        // level 2
        f32x2 ca2;
        ca2.x = (d0 - d1) * K;
        ca2.y = (d2 - d3) * K;
        float e0 = (d0 + d1) * K;
        float e1 = (d2 + d3) * K;

        // level 3
        float ca3 = (e0 - e1) * K;
        float cd3 = (e0 + e1) * K;

        o1[tp]   = ca1;      // coalesced float4
        o2[tp]   = ca2;      // coalesced float2
        o3[tp]   = ca3;      // coalesced float
        bufA[tp] = cd3;      // dense b32, 2 lanes/bank = conflict-free
    }
    __syncthreads();

    // ---- Level 4: 2048 -> 1024. Dense f32x4 reads (contiguous range).
    {
        f32x2* o4 = (f32x2*)(out + (size_t)NROWS * 14336 + (size_t)row * 1024);
        #pragma unroll
        for (int p = 0; p < 2; ++p) {
            const int idx = p * NT + tid;                // [0, 512)
            f32x4 v = ((const f32x4*)bufA)[idx];         // cD3[4i..4i+3]
            f32x2 ca = { (v.x - v.y) * K, (v.z - v.w) * K };
            f32x2 cd = { (v.x + v.y) * K, (v.z + v.w) * K };
            o4[idx] = ca;
            ((f32x2*)bufB)[idx] = cd;                    // dense: conflict-free
        }
    }
    __syncthreads();

    // ---- Level 5: 1024 -> 512.
    {
        f32x4 v = ((const f32x4*)bufB)[tid];             // cD4[4t..4t+3]
        f32x2 ca = { (v.x - v.y) * K, (v.z - v.w) * K };
        f32x2 cd = { (v.x + v.y) * K, (v.z + v.w) * K };
        f32x2* o5 = (f32x2*)(out + (size_t)NROWS * 15360 + (size_t)row * 512);
        o5[tid] = ca;
        ((f32x2*)bufA)[tid] = cd;
    }
    __syncthreads();

    // ---- Level 6: 512 -> 256.
    if (tid < 128) {
        f32x4 v = ((const f32x4*)bufA)[tid];             // cD5[4t..4t+3]
        f32x2 ca = { (v.x - v.y) * K, (v.z - v.w) * K };
        f32x2 cd = { (v.x + v.y) * K, (v.z + v.w) * K };
        f32x2* o6 = (f32x2*)(out + (size_t)NROWS * 15872 + (size_t)row * 256);
        o6[tid] = ca;
        ((f32x2*)bufB)[tid] = cd;
    }
    __syncthreads();

    // ---- Levels 7-14: wave 0 only; no further barriers needed.
    if (tid < 64) {
        // level 7 (128 outputs): read cD6[4t..4t+3]; the cD7 pair stays in
        // regs — lane t's cD7[2t], cD7[2t+1] are what level 8 lane t needs.
        f32x4 v = ((const f32x4*)bufB)[tid];
        f32x2 ca7 = { (v.x - v.y) * K, (v.z - v.w) * K };
        f32x2* o7 = (f32x2*)(out + (size_t)NROWS * 16128 + (size_t)row * 128);
        o7[tid] = ca7;
        float cd7a = (v.x + v.y) * K;
        float cd7b = (v.z + v.w) * K;

        // level 8 (64 outputs), purely in registers
        float* o8 = out + (size_t)NROWS * 16256 + (size_t)row * 64;
        o8[tid] = (cd7a - cd7b) * K;
        float x = (cd7a + cd7b) * K;     // cD8[lane]

        // levels 9-14 via cross-lane shuffle; lanes >= n carry garbage that is
        // never read (next level only sources lanes < 2n).
        size_t chunk = (size_t)NROWS * 16320;
        #pragma unroll
        for (int L = 9; L <= 14; ++L) {
            const int n = ROW_LEN >> L;               // 32,16,8,4,2,1
            float even = __shfl(x, 2 * tid,     64);
            float odd  = __shfl(x, 2 * tid + 1, 64);
            float ca = (even - odd) * K;
            x        = (even + odd) * K;
            if (tid < n) out[chunk + (size_t)row * n + tid] = ca;
            chunk += (size_t)NROWS * n;
        }
        // final approximation chunk: cD_14
        if (tid == 0) out[chunk + row] = x;
    }
}

extern "C" void kernel_launch(void* const* d_in, const int* in_sizes, int n_in,
                              void* d_out, int out_size, void* d_ws, size_t ws_size,
                              hipStream_t stream) {
    const float* x = (const float*)d_in[0];
    float* out = (float*)d_out;
    haar_kernel<<<dim3(NROWS), dim3(NT), 0, stream>>>(x, out);
}